// Round 1
// baseline (284.176 us; speedup 1.0000x reference)
//
#include <hip/hip_runtime.h>
#include <math.h>

#define B 32
#define Q 10000
#define C 80
#define TOPK 200

// ---------------------------------------------------------------------------
// Kernel 1: one wave (64 lanes) per (b,q) row of 80 logits.
//   score = 1 / sum(exp(l - max))   (double-precision exp+sum for ordering
//                                    fidelity vs the np reference)
//   class = argmax (first occurrence)
// Emits sortable 64-bit key: (score_bits << 32) | (0xFFFFFFFF - q)
//   -> descending key order == (score desc, q asc) == stable argsort(-scores)
// ---------------------------------------------------------------------------
__global__ __launch_bounds__(256) void score_kernel(
    const float* __restrict__ logits,
    unsigned long long* __restrict__ keys,
    int* __restrict__ cls_out)
{
    const int lane = threadIdx.x & 63;
    const int row  = blockIdx.x * 4 + (threadIdx.x >> 6);   // 4 waves/block
    const float* rp = logits + (long long)row * C;

    float v0 = rp[lane];                                    // elements 0..63
    float v1 = (lane < 16) ? rp[64 + lane] : -INFINITY;     // elements 64..79

    // wave max (exact)
    float m = fmaxf(v0, v1);
#pragma unroll
    for (int off = 32; off; off >>= 1)
        m = fmaxf(m, __shfl_xor(m, off, 64));

    // argmax, first occurrence (smallest index among maxima)
    int cand = 0x7FFFFFFF;
    if (lane < 16 && v1 == m) cand = 64 + lane;
    if (v0 == m)              cand = lane;
#pragma unroll
    for (int off = 32; off; off >>= 1)
        cand = min(cand, __shfl_xor(cand, off, 64));

    // sum of exp in double (f32 diffs are exact in f64)
    double e = exp((double)v0 - (double)m);
    if (lane < 16) e += exp((double)v1 - (double)m);
#pragma unroll
    for (int off = 32; off; off >>= 1)
        e += __shfl_xor(e, off, 64);

    if (lane == 0) {
        float sumf  = (float)e;
        float score = 1.0f / sumf;                 // score in (0,1]
        unsigned int sb = __float_as_uint(score);  // order-monotone bits
        unsigned int q  = (unsigned)(row % Q);
        keys[row]    = ((unsigned long long)sb << 32) |
                       (unsigned long long)(0xFFFFFFFFu - q);
        cls_out[row] = cand;
    }
}

// ---------------------------------------------------------------------------
// Kernel 2: one block (256 threads) per batch.
//   1) 2048-bucket histogram on top-13 score bits -> threshold bucket so that
//      candidates-above >= 200
//   2) collect candidates into LDS (cap 4096), bitonic sort descending
//   3) take first 200, build 200x200 suppression bitmatrix, serial greedy scan
// ---------------------------------------------------------------------------
__global__ __launch_bounds__(256) void nms_kernel(
    const unsigned long long* __restrict__ keys,
    const int*   __restrict__ classes,
    const float* __restrict__ seg,
    int*         __restrict__ out)
{
    __shared__ unsigned int        hist[2048];
    __shared__ unsigned long long  skey[4096];
    __shared__ int   s_count;
    __shared__ unsigned int s_thresh;
    __shared__ int   cidx[TOPK];
    __shared__ int   ccls[TOPK];
    __shared__ float cx1[TOPK], cx2[TOPK];
    __shared__ unsigned long long sup[TOPK][4];
    __shared__ int   keepArr[TOPK];
    __shared__ int   s_keepCount;

    const int b   = blockIdx.x;
    const int tid = threadIdx.x;
    const unsigned long long* bk = keys + (long long)b * Q;

    for (int i = tid; i < 2048; i += 256) hist[i] = 0;
    if (tid == 0) s_count = 0;
    __syncthreads();

    // pass 1: histogram of top 13 bits of score pattern (<= 0x3F800000>>19 = 2032)
    for (int i = tid; i < Q; i += 256) {
        unsigned int bits = (unsigned int)(bk[i] >> 32);
        atomicAdd(&hist[bits >> 19], 1u);
    }
    __syncthreads();

    if (tid == 0) {
        int acc = 0; unsigned int t = 0;
        for (int bkt = 2047; bkt >= 0; --bkt) {
            acc += (int)hist[bkt];
            if (acc >= TOPK) { t = (unsigned int)bkt; break; }
        }
        s_thresh = t;
    }
    __syncthreads();
    const unsigned int tb = s_thresh;

    // pass 2: collect all candidates in buckets >= threshold
    for (int i = tid; i < Q; i += 256) {
        unsigned long long k = bk[i];
        if (((unsigned int)(k >> 32) >> 19) >= tb) {
            int pos = atomicAdd(&s_count, 1);
            if (pos < 4096) skey[pos] = k;
        }
    }
    __syncthreads();

    int count = min(s_count, 4096);
    int M = 256;
    while (M < count) M <<= 1;
    for (int i = tid; i < M; i += 256)
        if (i >= count) skey[i] = 0;     // zero keys sort to the end
    __syncthreads();

    // bitonic sort, descending
    for (int k = 2; k <= M; k <<= 1) {
        for (int j = k >> 1; j > 0; j >>= 1) {
            for (int t = tid; t < M; t += 256) {
                int ixj = t ^ j;
                if (ixj > t) {
                    unsigned long long a = skey[t], c2 = skey[ixj];
                    bool desc = ((t & k) == 0);
                    bool sw   = desc ? (a < c2) : (a > c2);
                    if (sw) { skey[t] = c2; skey[ixj] = a; }
                }
            }
            __syncthreads();
        }
    }

    // gather top-200 candidate metadata
    if (tid < TOPK) {
        unsigned long long k = skey[tid];
        int q = (int)(0xFFFFFFFFu - (unsigned int)k);
        cidx[tid] = q;
        ccls[tid] = classes[b * Q + q];
        cx1[tid]  = seg[((long long)b * Q + q) * 2 + 0];
        cx2[tid]  = seg[((long long)b * Q + q) * 2 + 1];
    }
    __syncthreads();

    // suppression bitmatrix: sup[i][w] bit b -> j = w*64+b suppressed by i
    for (int w = tid; w < TOPK * 4; w += 256) {
        int i  = w >> 2, ww = w & 3;
        int jb = ww * 64;
        float x1 = cx1[i], x2 = cx2[i];
        int   ci = ccls[i];
        unsigned long long bits = 0ull;
        for (int bb = 0; bb < 64; ++bb) {
            int j = jb + bb;
            if (j < TOPK && j > i) {
                float inter = fminf(x2, cx2[j]) - fmaxf(x1, cx1[j]);
                if (inter > 0.0f && ccls[j] == ci)
                    bits |= (1ull << bb);
            }
        }
        sup[i][ww] = bits;
    }
    __syncthreads();

    // greedy serial scan (exactly the reference loop)
    if (tid == 0) {
        unsigned long long act[4] = { ~0ull, ~0ull, ~0ull, ~0ull };
        int kc = 0;
        for (int p = 0; p < TOPK; ++p) {
            if ((act[p >> 6] >> (p & 63)) & 1ull) {
                keepArr[kc++] = cidx[p];
                act[0] &= ~sup[p][0];
                act[1] &= ~sup[p][1];
                act[2] &= ~sup[p][2];
                act[3] &= ~sup[p][3];
            }
        }
        s_keepCount = kc;
    }
    __syncthreads();

    const int kc = s_keepCount;
    if (tid < TOPK) {
        out[b * TOPK + tid]       = (tid < kc) ? keepArr[tid] : -1;
        out[(B + b) * TOPK + tid] = 0;   // zeros half of the concat
    }
}

extern "C" void kernel_launch(void* const* d_in, const int* in_sizes, int n_in,
                              void* d_out, int out_size, void* d_ws, size_t ws_size,
                              hipStream_t stream)
{
    const float* logits = (const float*)d_in[0];   // [B,Q,C] fp32
    const float* seg    = (const float*)d_in[1];   // [B,Q,2] fp32
    int* out = (int*)d_out;                        // [2B, TOPK] int32

    unsigned long long* keys = (unsigned long long*)d_ws;                 // B*Q*8
    int* classes = (int*)((char*)d_ws + (size_t)B * Q * sizeof(unsigned long long));

    score_kernel<<<(B * Q) / 4, 256, 0, stream>>>(logits, keys, classes);
    nms_kernel<<<B, 256, 0, stream>>>(keys, classes, seg, out);
}

// Round 2
// 196.760 us; speedup vs baseline: 1.4443x; 1.4443x over previous
//
#include <hip/hip_runtime.h>
#include <math.h>

#define B 32
#define Q 10000
#define C 80
#define TOPK 200

// ---------------------------------------------------------------------------
// Fast double-precision exp for x in [-40, 0]:
//   y = x*log2(e); n = rint(y) (magic-shift); f = y-n; r = f*ln2
//   exp(x) = 2^n * Horner9(r)     (abs rel error ~7e-12)
// No branches, no denormals in range (result >= exp(-40) ~ 4e-18, exp>=2^-58).
// ---------------------------------------------------------------------------
__device__ __forceinline__ double fexp(double x) {
    const double L2E   = 1.4426950408889634;      // log2(e)
    const double SHIFT = 6755399441055744.0;      // 1.5 * 2^52
    const double LN2   = 0.6931471805599453;

    double y = x * L2E;
    double t = y + SHIFT;
    union { double d; unsigned long long u; } cv;
    cv.d = t;
    int n = (int)(unsigned int)cv.u;              // low 32 bits = rint(y)
    double f = y - (t - SHIFT);                   // f in [-0.5, 0.5]
    double r = f * LN2;

    double p = 2.755731922398589e-06;             // 1/9!
    p = fma(p, r, 2.4801587301587302e-05);        // 1/8!
    p = fma(p, r, 1.984126984126984e-04);         // 1/7!
    p = fma(p, r, 1.3888888888888889e-03);        // 1/6!
    p = fma(p, r, 8.333333333333333e-03);         // 1/5!
    p = fma(p, r, 4.1666666666666664e-02);        // 1/4!
    p = fma(p, r, 1.6666666666666666e-01);        // 1/3!
    p = fma(p, r, 0.5);                           // 1/2!
    p = fma(p, r, 1.0);
    p = fma(p, r, 1.0);

    cv.d = p;
    cv.u += ((unsigned long long)(long long)n) << 52;   // scale by 2^n
    return cv.d;
}

// ---------------------------------------------------------------------------
// Kernel 1: ONE THREAD per (b,q) row of 80 logits. Row lives in registers
// (20 x float4). score = 1/sum(exp(l-m)) with f64 poly exp; class = first-
// occurrence argmax. Key: (score_bits<<32) | (0xFFFFFFFF - q)  -> descending
// key order == stable argsort(-scores).
// ---------------------------------------------------------------------------
__global__ __launch_bounds__(256) void score_kernel(
    const float* __restrict__ logits,
    unsigned long long* __restrict__ keys,
    int* __restrict__ cls_out)
{
    const int row = blockIdx.x * 256 + threadIdx.x;      // grid covers B*Q exactly
    const float4* rp = (const float4*)(logits + (long long)row * C);

    float4 v[20];
#pragma unroll
    for (int i = 0; i < 20; ++i) v[i] = rp[i];

    // max + first-occurrence argmax (sequential scan, strict >)
    float m = -INFINITY; int idx = 0;
#pragma unroll
    for (int i = 0; i < 20; ++i) {
        if (v[i].x > m) { m = v[i].x; idx = 4*i + 0; }
        if (v[i].y > m) { m = v[i].y; idx = 4*i + 1; }
        if (v[i].z > m) { m = v[i].z; idx = 4*i + 2; }
        if (v[i].w > m) { m = v[i].w; idx = 4*i + 3; }
    }

    const double md = (double)m;
    double s = 0.0;
#pragma unroll
    for (int i = 0; i < 20; ++i) {
        s += fexp((double)v[i].x - md);
        s += fexp((double)v[i].y - md);
        s += fexp((double)v[i].z - md);
        s += fexp((double)v[i].w - md);
    }

    float sumf  = (float)s;
    float score = 1.0f / sumf;                    // identical final rounding to R1
    unsigned int sb = __float_as_uint(score);     // order-monotone bits (score>0)
    unsigned int q  = (unsigned)(row % Q);
    keys[row]    = ((unsigned long long)sb << 32) |
                   (unsigned long long)(0xFFFFFFFFu - q);
    cls_out[row] = idx;
}

// ---------------------------------------------------------------------------
// Kernel 2: one block (1024 threads) per batch.
//   1) 2048-bucket histogram on top-13 score bits; two-level threshold scan
//   2) collect candidates >= threshold bucket into LDS, bitonic sort desc
//   3) top-200 -> 200x200 suppression bitmatrix -> serial greedy scan
// ---------------------------------------------------------------------------
__global__ __launch_bounds__(1024) void nms_kernel(
    const unsigned long long* __restrict__ keys,
    const int*   __restrict__ classes,
    const float* __restrict__ seg,
    int*         __restrict__ out)
{
    __shared__ unsigned int        hist[2048];
    __shared__ int                 chunk[256];
    __shared__ unsigned long long  skey[4096];
    __shared__ int   s_count;
    __shared__ unsigned int s_thresh;
    __shared__ int   cidx[TOPK];
    __shared__ int   ccls[TOPK];
    __shared__ float cx1[TOPK], cx2[TOPK];
    __shared__ unsigned long long sup[TOPK][4];
    __shared__ int   keepArr[TOPK];
    __shared__ int   s_keepCount;

    const int b   = blockIdx.x;
    const int tid = threadIdx.x;
    const unsigned long long* bk = keys + (long long)b * Q;

    for (int i = tid; i < 2048; i += 1024) hist[i] = 0;
    if (tid == 0) s_count = 0;
    __syncthreads();

    // pass 1: histogram of top 13 bits of score pattern
    for (int i = tid; i < Q; i += 1024) {
        unsigned int bits = (unsigned int)(bk[i] >> 32);
        atomicAdd(&hist[bits >> 19], 1u);
    }
    __syncthreads();

    // two-level threshold scan (chunk sums in parallel, short serial tail)
    if (tid < 256) {
        int cs = 0;
#pragma unroll
        for (int j = 0; j < 8; ++j) cs += (int)hist[tid * 8 + j];
        chunk[tid] = cs;
    }
    __syncthreads();

    if (tid == 0) {
        int acc = 0; unsigned int t = 0; int ck = -1;
        for (int c = 255; c >= 0; --c) {
            if (acc + chunk[c] >= TOPK) { ck = c; break; }
            acc += chunk[c];
        }
        if (ck >= 0) {
            for (int j = 7; j >= 0; --j) {
                acc += (int)hist[ck * 8 + j];
                if (acc >= TOPK) { t = (unsigned int)(ck * 8 + j); break; }
            }
        }
        s_thresh = t;
    }
    __syncthreads();
    const unsigned int tb = s_thresh;

    // pass 2: collect all candidates in buckets >= threshold
    for (int i = tid; i < Q; i += 1024) {
        unsigned long long k = bk[i];
        if (((unsigned int)(k >> 32) >> 19) >= tb) {
            int pos = atomicAdd(&s_count, 1);
            if (pos < 4096) skey[pos] = k;
        }
    }
    __syncthreads();

    int count = min(s_count, 4096);
    int M = 256;
    while (M < count) M <<= 1;
    for (int i = tid; i < M; i += 1024)
        if (i >= count) skey[i] = 0;     // zero keys sort to the end
    __syncthreads();

    // bitonic sort, descending
    for (int k = 2; k <= M; k <<= 1) {
        for (int j = k >> 1; j > 0; j >>= 1) {
            for (int t = tid; t < M; t += 1024) {
                int ixj = t ^ j;
                if (ixj > t) {
                    unsigned long long a = skey[t], c2 = skey[ixj];
                    bool desc = ((t & k) == 0);
                    bool sw   = desc ? (a < c2) : (a > c2);
                    if (sw) { skey[t] = c2; skey[ixj] = a; }
                }
            }
            __syncthreads();
        }
    }

    // gather top-200 candidate metadata
    if (tid < TOPK) {
        unsigned long long k = skey[tid];
        int q = (int)(0xFFFFFFFFu - (unsigned int)k);
        cidx[tid] = q;
        ccls[tid] = classes[b * Q + q];
        cx1[tid]  = seg[((long long)b * Q + q) * 2 + 0];
        cx2[tid]  = seg[((long long)b * Q + q) * 2 + 1];
    }
    __syncthreads();

    // suppression bitmatrix: sup[i][w] bit bb -> j = w*64+bb suppressed by i
    for (int w = tid; w < TOPK * 4; w += 1024) {
        int i  = w >> 2, ww = w & 3;
        int jb = ww * 64;
        float x1 = cx1[i], x2 = cx2[i];
        int   ci = ccls[i];
        unsigned long long bits = 0ull;
        for (int bb = 0; bb < 64; ++bb) {
            int j = jb + bb;
            if (j < TOPK && j > i) {
                float inter = fminf(x2, cx2[j]) - fmaxf(x1, cx1[j]);
                if (inter > 0.0f && ccls[j] == ci)
                    bits |= (1ull << bb);
            }
        }
        sup[i][ww] = bits;
    }
    __syncthreads();

    // greedy serial scan (exactly the reference loop)
    if (tid == 0) {
        unsigned long long act[4] = { ~0ull, ~0ull, ~0ull, ~0ull };
        int kc = 0;
        for (int p = 0; p < TOPK; ++p) {
            if ((act[p >> 6] >> (p & 63)) & 1ull) {
                keepArr[kc++] = cidx[p];
                act[0] &= ~sup[p][0];
                act[1] &= ~sup[p][1];
                act[2] &= ~sup[p][2];
                act[3] &= ~sup[p][3];
            }
        }
        s_keepCount = kc;
    }
    __syncthreads();

    const int kc = s_keepCount;
    if (tid < TOPK) {
        out[b * TOPK + tid]       = (tid < kc) ? keepArr[tid] : -1;
        out[(B + b) * TOPK + tid] = 0;   // zeros half of the concat
    }
}

extern "C" void kernel_launch(void* const* d_in, const int* in_sizes, int n_in,
                              void* d_out, int out_size, void* d_ws, size_t ws_size,
                              hipStream_t stream)
{
    const float* logits = (const float*)d_in[0];   // [B,Q,C] fp32
    const float* seg    = (const float*)d_in[1];   // [B,Q,2] fp32
    int* out = (int*)d_out;                        // [2B, TOPK] int32

    unsigned long long* keys = (unsigned long long*)d_ws;                 // B*Q*8
    int* classes = (int*)((char*)d_ws + (size_t)B * Q * sizeof(unsigned long long));

    score_kernel<<<(B * Q) / 256, 256, 0, stream>>>(logits, keys, classes);
    nms_kernel<<<B, 1024, 0, stream>>>(keys, classes, seg, out);
}

// Round 3
// 191.394 us; speedup vs baseline: 1.4848x; 1.0280x over previous
//
#include <hip/hip_runtime.h>
#include <math.h>

#define B 32
#define Q 10000
#define C 80
#define TOPK 200

// ---------------------------------------------------------------------------
// Fast double-precision exp for x in [-40, 0]  (identical bits to R2 version)
// ---------------------------------------------------------------------------
__device__ __forceinline__ double fexp(double x) {
    const double L2E   = 1.4426950408889634;      // log2(e)
    const double SHIFT = 6755399441055744.0;      // 1.5 * 2^52
    const double LN2   = 0.6931471805599453;

    double y = x * L2E;
    double t = y + SHIFT;
    union { double d; unsigned long long u; } cv;
    cv.d = t;
    int n = (int)(unsigned int)cv.u;              // low 32 bits = rint(y)
    double f = y - (t - SHIFT);                   // f in [-0.5, 0.5]
    double r = f * LN2;

    double p = 2.755731922398589e-06;             // 1/9!
    p = fma(p, r, 2.4801587301587302e-05);
    p = fma(p, r, 1.984126984126984e-04);
    p = fma(p, r, 1.3888888888888889e-03);
    p = fma(p, r, 8.333333333333333e-03);
    p = fma(p, r, 4.1666666666666664e-02);
    p = fma(p, r, 1.6666666666666666e-01);
    p = fma(p, r, 0.5);
    p = fma(p, r, 1.0);
    p = fma(p, r, 1.0);

    cv.d = p;
    cv.u += ((unsigned long long)(long long)n) << 52;
    return cv.d;
}

// ---------------------------------------------------------------------------
// Kernel 1 v3: 64-thread block stages 64 rows (20.25 KB LDS, stride 81 dwords
// -> conflict-free reads) via fully COALESCED dwordx4 global loads, then
// thread t computes row t from LDS. Key bits identical to R2 (same fexp,
// same sequential sum order).
// ---------------------------------------------------------------------------
__global__ __launch_bounds__(64) void score_kernel(
    const float* __restrict__ logits,
    unsigned long long* __restrict__ keys,
    int* __restrict__ cls_out)
{
    __shared__ float sb[64 * 81];
    const int t = threadIdx.x;                       // 0..63
    const int rowBase = blockIdx.x * 64;
    const float4* src = (const float4*)(logits + (long long)rowBase * C);

#pragma unroll
    for (int i = 0; i < 20; ++i) {
        int g = i * 64 + t;                          // float4 index in 1280-chunk
        float4 v = src[g];                           // coalesced: lane-contiguous
        int r = g / 20;
        int c = (g % 20) * 4;
        float* d = &sb[r * 81 + c];
        d[0] = v.x; d[1] = v.y; d[2] = v.z; d[3] = v.w;
    }
    __syncthreads();

    const float* row = &sb[t * 81];                  // banks 17*t mod 32: conflict-free

    float m = -INFINITY; int idx = 0;
#pragma unroll 8
    for (int j = 0; j < 80; ++j) {
        float v = row[j];
        if (v > m) { m = v; idx = j; }               // strict >: first occurrence
    }

    const double md = (double)m;
    double s = 0.0;
#pragma unroll 8
    for (int j = 0; j < 80; ++j)
        s += fexp((double)row[j] - md);              // sequential order == R2

    float sumf  = (float)s;
    float score = 1.0f / sumf;
    unsigned int sbits = __float_as_uint(score);
    int grow = rowBase + t;
    unsigned int q = (unsigned)(grow % Q);
    keys[grow]    = ((unsigned long long)sbits << 32) |
                    (unsigned long long)(0xFFFFFFFFu - q);
    cls_out[grow] = idx;
}

// ---------------------------------------------------------------------------
// Kernel 2 v3: one block (1024 threads) per batch.
//   histogram -> wave-parallel threshold (shuffle suffix-scan + ballot)
//   -> ballot-aggregated collect -> bitonic sort -> sup bitmatrix
//   -> register-resident wave-parallel greedy scan -> parallel compaction
// ---------------------------------------------------------------------------
__global__ __launch_bounds__(1024) void nms_kernel(
    const unsigned long long* __restrict__ keys,
    const int*   __restrict__ classes,
    const float* __restrict__ seg,
    int*         __restrict__ out)
{
    __shared__ unsigned int        hist[2048];
    __shared__ unsigned long long  skey[4096];
    __shared__ int   s_count;
    __shared__ unsigned int s_thresh;
    __shared__ int   cidx[TOPK];
    __shared__ int   ccls[TOPK];
    __shared__ float cx1[TOPK], cx2[TOPK];
    __shared__ unsigned long long sup[TOPK][4];
    __shared__ int   keepArr[TOPK];
    __shared__ int   s_keepCount;

    const int b   = blockIdx.x;
    const int tid = threadIdx.x;
    const unsigned long long* bk = keys + (long long)b * Q;

    for (int i = tid; i < 2048; i += 1024) hist[i] = 0;
    if (tid == 0) s_count = 0;
    __syncthreads();

    // histogram of top 13 bits of score pattern
    for (int i = tid; i < Q; i += 1024) {
        unsigned int bits = (unsigned int)(bk[i] >> 32);
        atomicAdd(&hist[bits >> 19], 1u);
    }
    __syncthreads();

    // threshold: wave-0 two-level suffix scan
    if (tid < 64) {
        int cs = 0;
#pragma unroll
        for (int k = 0; k < 32; ++k) cs += (int)hist[tid * 32 + k];
        int S = cs;                                   // suffix-inclusive over lanes
#pragma unroll
        for (int off = 1; off < 64; off <<= 1) {
            int o = __shfl_down(S, off, 64);
            if (tid + off < 64) S += o;
        }
        unsigned long long bal = __ballot(S >= TOPK); // bit0 always set (S_0 = Q)
        int L = 63 - __clzll(bal);                    // chunk containing threshold
        int accBase = (L < 63) ? __shfl(S, L + 1, 64) : 0;

        int h = (tid < 32) ? (int)hist[L * 32 + tid] : 0;
        int T = h;                                    // suffix within chunk
#pragma unroll
        for (int off = 1; off < 32; off <<= 1) {
            int o = __shfl_down(T, off, 64);
            if (tid + off < 32) T += o;
        }
        unsigned long long bal2 = __ballot((tid < 32) && (accBase + T >= TOPK));
        int k2 = 63 - __clzll(bal2);
        if (tid == 0) s_thresh = (unsigned)(L * 32 + k2);
    }
    __syncthreads();
    const unsigned int tb = s_thresh;

    // collect candidates >= threshold bucket (ballot-aggregated atomic)
    for (int i = tid; i < 10240; i += 1024) {
        unsigned long long k = (i < Q) ? bk[i] : 0ull;
        bool pred = (i < Q) && (((unsigned int)(k >> 32) >> 19) >= tb);
        unsigned long long mask = __ballot(pred);
        int lane = tid & 63;
        int base;
        if (lane == 0) base = atomicAdd(&s_count, __popcll(mask));
        base = __shfl(base, 0, 64);
        if (pred) {
            int pos = base + __popcll(mask & ((1ull << lane) - 1ull));
            if (pos < 4096) skey[pos] = k;
        }
    }
    __syncthreads();

    int count = min(s_count, 4096);
    int M = 256;
    while (M < count) M <<= 1;
    for (int i = tid; i < M; i += 1024)
        if (i >= count) skey[i] = 0;
    __syncthreads();

    // bitonic sort, descending
    for (int k = 2; k <= M; k <<= 1) {
        for (int j = k >> 1; j > 0; j >>= 1) {
            for (int t2 = tid; t2 < M; t2 += 1024) {
                int ixj = t2 ^ j;
                if (ixj > t2) {
                    unsigned long long a = skey[t2], c2 = skey[ixj];
                    bool desc = ((t2 & k) == 0);
                    bool sw   = desc ? (a < c2) : (a > c2);
                    if (sw) { skey[t2] = c2; skey[ixj] = a; }
                }
            }
            __syncthreads();
        }
    }

    // gather top-200 candidate metadata
    if (tid < TOPK) {
        unsigned long long k = skey[tid];
        int q = (int)(0xFFFFFFFFu - (unsigned int)k);
        cidx[tid] = q;
        ccls[tid] = classes[b * Q + q];
        cx1[tid]  = seg[((long long)b * Q + q) * 2 + 0];
        cx2[tid]  = seg[((long long)b * Q + q) * 2 + 1];
    }
    __syncthreads();

    // suppression bitmatrix: sup[i][w] bit bb -> j = w*64+bb suppressed by i
    for (int w2 = tid; w2 < TOPK * 4; w2 += 1024) {
        int i  = w2 >> 2, ww = w2 & 3;
        int jb = ww * 64;
        float x1 = cx1[i], x2 = cx2[i];
        int   ci = ccls[i];
        unsigned long long bits = 0ull;
        for (int bb = 0; bb < 64; ++bb) {
            int j = jb + bb;
            if (j < TOPK && j > i) {
                float inter = fminf(x2, cx2[j]) - fmaxf(x1, cx1[j]);
                if (inter > 0.0f && ccls[j] == ci)
                    bits |= (1ull << bb);
            }
        }
        sup[i][ww] = bits;
    }
    __syncthreads();

    // greedy scan, wave-parallel: sup matrix register-resident in wave 0.
    // word (p,w) = p*4+w lives at reg g = p/16, lane 4*(p%16)+w.
    if (tid < 64) {
        unsigned long long w[13];
#pragma unroll
        for (int r = 0; r < 13; ++r) {
            int wg = r * 64 + tid;
            w[r] = (wg < TOPK * 4) ? sup[wg >> 2][wg & 3] : 0ull;
        }
        unsigned long long act[4]  = { ~0ull, ~0ull, ~0ull, ~0ull };
        unsigned long long kept[4] = { 0ull, 0ull, 0ull, 0ull };
#pragma unroll
        for (int g = 0; g < 13; ++g) {
#pragma unroll
            for (int s2 = 0; s2 < 16; ++s2) {
                const int p = g * 16 + s2;
                if (p >= TOPK) break;
                if ((act[p >> 6] >> (p & 63)) & 1ull) {   // replicated -> uniform
                    kept[p >> 6] |= 1ull << (p & 63);
                    unsigned long long s0 = __shfl(w[g], 4 * s2 + 0, 64);
                    unsigned long long s1 = __shfl(w[g], 4 * s2 + 1, 64);
                    unsigned long long sv = __shfl(w[g], 4 * s2 + 2, 64);
                    unsigned long long s3 = __shfl(w[g], 4 * s2 + 3, 64);
                    act[0] &= ~s0; act[1] &= ~s1; act[2] &= ~sv; act[3] &= ~s3;
                }
            }
        }
        // parallel compaction of the keep list
        int base0 = 0;
#pragma unroll
        for (int r = 0; r < 4; ++r) {
            int p = r * 64 + tid;
            if (p < TOPK && ((kept[r] >> tid) & 1ull)) {
                int slot = base0 + __popcll(kept[r] & ((1ull << tid) - 1ull));
                keepArr[slot] = cidx[p];
            }
            base0 += __popcll(kept[r]);
        }
        if (tid == 0) s_keepCount = base0;
    }
    __syncthreads();

    const int kc = s_keepCount;
    if (tid < TOPK) {
        out[b * TOPK + tid]       = (tid < kc) ? keepArr[tid] : -1;
        out[(B + b) * TOPK + tid] = 0;
    }
}

extern "C" void kernel_launch(void* const* d_in, const int* in_sizes, int n_in,
                              void* d_out, int out_size, void* d_ws, size_t ws_size,
                              hipStream_t stream)
{
    const float* logits = (const float*)d_in[0];   // [B,Q,C] fp32
    const float* seg    = (const float*)d_in[1];   // [B,Q,2] fp32
    int* out = (int*)d_out;                        // [2B, TOPK] int32

    unsigned long long* keys = (unsigned long long*)d_ws;                 // B*Q*8
    int* classes = (int*)((char*)d_ws + (size_t)B * Q * sizeof(unsigned long long));

    score_kernel<<<(B * Q) / 64, 64, 0, stream>>>(logits, keys, classes);
    nms_kernel<<<B, 1024, 0, stream>>>(keys, classes, seg, out);
}